// Round 3
// baseline (332.250 us; speedup 1.0000x reference)
//
#include <hip/hip_runtime.h>
#include <hip/hip_bf16.h>

// out[i, r, c] = dot(q[i, r, :], e[h, L-1-(r-c), :])  for c <= r, else 0
// T[r, n] = q[r,:] . e_rev[n,:]  (n = r - c).
//
// Same row-strip MFMA + skewed-LDS structure as round 2, plus:
//  * PHASE-ROTATED chunk order: each wave visits its 64-col chunks in order
//    ch = ((start + t) & 7)*4 + par with a per-wave hash `start`, so the
//    chip-wide store stream is spread across all HBM channels instead of
//    every wave hammering the same 256-B column window in lockstep
//    (address bits [12:0] = c*4 -> channel bits come from c only).
//  * mod-4 chunk ownership (4096 waves, 2 blocks/CU, 16 waves/CU) for
//    deeper store-queue coverage.
//
// Per chunk (cols [c0, c0+64)): diagonals n = r-c span [M-63, M+15],
// M = s0-c0 >= 0 -> 5 MFMA n-subtiles covering [M-64, M+16) (subtiles with
// all n<0 skipped via tmin; partial subtile starts exactly at n=0 so no OOB
// e reads).  Strip staged into a per-wave SKEWED LDS slice:
//     T[s0+rr, n] -> ldsw[rr][g],  g = n - rr + (79 - M)
// so the output read column g = 79 - (c - c0) is row-independent -> aligned
// f32x4 read (reversed) -> one 16 B nontemporal store per thread per iter.
// No __syncthreads anywhere (waves touch only their own LDS slice).
// Stale LDS from skipped/previous chunks lies entirely in the masked c>r
// region.  Balance: strip k pairs with strip 127-k (33 compute chunks per
// pair); each pair split across 4 waves by chunk index mod 4.

typedef __bf16 bf16x8 __attribute__((ext_vector_type(8)));
typedef float  f32x4  __attribute__((ext_vector_type(4)));
typedef float  f32x8  __attribute__((ext_vector_type(8)));

constexpr int L   = 2048;
constexpr int D   = 64;
constexpr int LDW = 100;    // LDS row stride in floats (g in [0,94] + pad)

__device__ __forceinline__ bf16x8 load_cvt8(const float* __restrict__ p) {
  f32x8 v = *(const f32x8*)p;       // 2x global_load_dwordx4
  bf16x8 r;
#pragma unroll
  for (int k = 0; k < 8; ++k) r[k] = (__bf16)v[k];
  return r;
}

__global__ __launch_bounds__(512) void skew_rows(const float* __restrict__ q,
                                                 const float* __restrict__ e,
                                                 float* __restrict__ out) {
  const int tid  = threadIdx.x;
  const int lane = tid & 63;
  const int w    = tid >> 6;        // wave 0..7
  const int ln   = lane & 15;
  const int quad = lane >> 4;
  const int i = blockIdx.x;         // bh index, h = i & 7
  const int h = i & 7;
  const int pp  = blockIdx.y * 2 + (w >> 2);   // strip pair 0..63
  const int par = w & 3;                       // chunk class (mod 4)

  __shared__ __align__(16) float lds[8 * 16 * LDW];   // 51.2 KB, per-wave slices
  float* ldsw  = &lds[w * (16 * LDW)];
  float* obase = out + (size_t)i * L * L;

#pragma unroll 1
  for (int sp = 0; sp < 2; ++sp) {
    const int sidx = sp ? (127 - pp) : pp;   // strip index 0..127
    const int s0   = sidx << 4;              // first row of strip
    const int nch  = (sidx >> 2) + 1;        // chunks containing lower-tri data

    // per-wave column-phase hash (decorrelate channel usage chip-wide)
    const int start = ((i * 3 + pp * 7 + par * 2 + sp) * 5) & 7;

    // ---- A fragments: lane holds q[s0+ln][quad*8 + k] (held across sweep) ----
    const float* qp = q + ((size_t)(i * L + s0 + ln)) * D + (quad << 3);
    const bf16x8 a0 = load_cvt8(qp);
    const bf16x8 a1 = load_cvt8(qp + 32);

#pragma unroll 1
    for (int t = 0; t < 8; ++t) {
      const int ch = (((start + t) & 7) << 2) + par;   // this wave's chunks
      const int c0 = ch << 6;
      float* orow = obase + (size_t)s0 * L + c0;

      if (ch < nch) {
        // ---- compute chunk ----
        const int M    = s0 - c0;                          // >= 0
        const int tmin = (M >= 64) ? 0 : ((64 - M) >> 4);  // skip all-(n<0) subtiles

        // B loads + MFMA: subtile t covers n = M-64+16t+ln, erow = L-1-n
        const float* ep = e + ((size_t)(h * L + (2111 - M - ln))) * D + (quad << 3);
        f32x4 acc[5];
#pragma unroll
        for (int tt = 0; tt < 5; ++tt) {
          if (tt < tmin) continue;
          const float* ept = ep - (tt << 10);    // -16t e-rows (1024 floats)
          bf16x8 b0 = load_cvt8(ept);
          bf16x8 b1 = load_cvt8(ept + 32);
          f32x4 z = {0.f, 0.f, 0.f, 0.f};
          z       = __builtin_amdgcn_mfma_f32_16x16x32_bf16(a0, b0, z, 0, 0, 0);
          acc[tt] = __builtin_amdgcn_mfma_f32_16x16x32_bf16(a1, b1, z, 0, 0, 0);
        }

        // skewed LDS stage: C-frag row = quad*4+jr, col n = (M-64+16t)+ln
        // float idx = row*LDW + g, g = 15 + 16t + ln - 4*quad - jr
        const int lbase = quad * (4 * LDW - 4) + ln + 15;
#pragma unroll
        for (int tt = 0; tt < 5; ++tt) {
          if (tt < tmin) continue;
#pragma unroll
          for (int jr = 0; jr < 4; ++jr)
            ldsw[lbase + jr * (LDW - 1) + (tt << 4)] = acc[tt][jr];
        }

        // diagonal-aligned reads + 16 B stores; mask c>r iff chunk hits diag
        // (also covers stale LDS from skipped/previous chunks)
        const bool mask = (M < 64);
#pragma unroll
        for (int it = 0; it < 4; ++it) {
          const int idx = (it << 6) + lane;
          const int rr  = idx >> 4;
          const int jj  = idx & 15;
          const f32x4 v = *(const f32x4*)&ldsw[rr * LDW + 76 - (jj << 2)];
          f32x4 o = { v[3], v[2], v[1], v[0] };
          if (mask) {
            const int lim = M + rr - (jj << 2);   // t2 > lim  ->  c > r
#pragma unroll
            for (int t2 = 0; t2 < 4; ++t2) if (t2 > lim) o[t2] = 0.f;
          }
          __builtin_nontemporal_store(
              o, (f32x4*)(orow + (size_t)rr * L + (jj << 2)));
        }
      } else {
        // ---- pure zero chunk (upper triangle) ----
        const f32x4 zz = {0.f, 0.f, 0.f, 0.f};
#pragma unroll
        for (int it = 0; it < 4; ++it) {
          const int idx = (it << 6) + lane;
          const int rr  = idx >> 4;
          const int jj  = idx & 15;
          __builtin_nontemporal_store(
              zz, (f32x4*)(orow + (size_t)rr * L + (jj << 2)));
        }
      }
    }
  }
}

extern "C" void kernel_launch(void* const* d_in, const int* in_sizes, int n_in,
                              void* d_out, int out_size, void* d_ws, size_t ws_size,
                              hipStream_t stream) {
  const float* q = (const float*)d_in[0];   // (2, 8, 2048, 64) fp32
  const float* e = (const float*)d_in[1];   // (8, 2048, 64) fp32
  float* out = (float*)d_out;               // (2, 8, 2048, 2048) fp32

  dim3 grid(16, 32);   // (bh, 2-pair group) -> 512 blocks, 8 waves each
  skew_rows<<<grid, 512, 0, stream>>>(q, e, out);
}

// Round 4
// 317.704 us; speedup vs baseline: 1.0458x; 1.0458x over previous
//
#include <hip/hip_runtime.h>
#include <hip/hip_bf16.h>

// out[i, r, c] = dot(q[i, r, :], e[h, L-1-(r-c), :])  for c <= r, else 0
// T[r, n] = q[r,:] . e_rev[n,:]  (n = r - c).
//
// SUPERCHUNK store retile: write bursts widened 256 B -> 1 KB (one full HBM
// page per burst).  Each wave owns 16-row strips; per 256-col superchunk it
// computes four 64-col chunks with MFMA and scatters the C-fragments
// DIRECTLY into a per-wave linear LDS row buffer lds2[16][288]
// (lcol = c - C + 16; chunk-overlap writes are bitwise-identical duplicates,
// left/right spill lands in the 16-float pads), then stores each row as one
// 64-lane x 16 B = 1 KB contiguous nontemporal wave-store (16 per sc).
// Upper-triangle zeros: 1 KB zero row-stores.  No __syncthreads anywhere.
//
// Per 64-chunk (validated algebra from rounds 0-2):
//   acc[tt][jr] = T[s0 + 4*quad + jr][ M - 64 + 16*tt + ln ],  M = s0 - c0
//   -> c = c0 + 64 - 16tt - ln + row,  row = 4*quad + jr
//   -> lds2 idx = row*(LDS2+1) + 64*sub + 80 - 16tt - ln   (lcol in [1,287])
// tmin skips all-(n<0) subtiles (M multiple of 16 -> partial subtile starts
// exactly at n = 0, no OOB e reads).  Diagonal superchunk: compute chunks
// sub <= q6, mask c > r at store (covers stale LDS above the diagonal).
//
// Balance: strip k pairs with 127-k -> 9 compute-sc per pair, split across
// the pair's 2 waves by sc parity.  Grid 16x16, 512 thr: 2048 waves,
// 147.5 KB LDS -> 1 block/CU, 2 waves/SIMD.

typedef __bf16 bf16x8 __attribute__((ext_vector_type(8)));
typedef float  f32x4  __attribute__((ext_vector_type(4)));
typedef float  f32x8  __attribute__((ext_vector_type(8)));

constexpr int L    = 2048;
constexpr int D    = 64;
constexpr int LDS2 = 288;   // floats per staged row: 16 pad | 256 data | 16 spill

__device__ __forceinline__ bf16x8 load_cvt8(const float* __restrict__ p) {
  f32x8 v = *(const f32x8*)p;       // 2x global_load_dwordx4
  bf16x8 r;
#pragma unroll
  for (int k = 0; k < 8; ++k) r[k] = (__bf16)v[k];
  return r;
}

__global__ __launch_bounds__(512) void skew_sc(const float* __restrict__ q,
                                               const float* __restrict__ e,
                                               float* __restrict__ out) {
  const int tid  = threadIdx.x;
  const int lane = tid & 63;
  const int w    = tid >> 6;        // wave 0..7
  const int ln   = lane & 15;
  const int quad = lane >> 4;
  const int i = blockIdx.x;         // bh index, h = i & 7
  const int h = i & 7;
  const int pp  = blockIdx.y * 4 + (w >> 1);   // strip pair 0..63
  const int par = w & 1;                       // superchunk parity

  __shared__ __align__(16) float lds[8 * 16 * LDS2];   // 147.5 KB, per-wave
  float* ldsw  = &lds[w * (16 * LDS2)];
  float* obase = out + (size_t)i * L * L;

#pragma unroll 1
  for (int sp = 0; sp < 2; ++sp) {
    const int sidx = sp ? (127 - pp) : pp;   // strip index 0..127
    const int s0   = sidx << 4;              // first row of strip
    const int scd  = sidx >> 4;              // superchunk holding the diagonal
    const int q6   = (sidx >> 2) & 3;        // last compute 64-chunk in scd

    // ---- A fragments: lane holds q[s0+ln][quad*8 + k] (held across sweep) ----
    const float* qp = q + ((size_t)(i * L + s0 + ln)) * D + (quad << 3);
    const bf16x8 a0 = load_cvt8(qp);
    const bf16x8 a1 = load_cvt8(qp + 32);

#pragma unroll 1
    for (int sc = par; sc < 8; sc += 2) {
      const int C = sc << 8;
      float* orow = obase + (size_t)s0 * L + C + (lane << 2);

      if (sc <= scd) {
        // ---- compute superchunk: 4 (or q6+1) chunks -> direct LDS scatter ----
        const int submax = (sc < scd) ? 3 : q6;
        const bool mask  = (sc == scd);
#pragma unroll 1
        for (int sub = 0; sub <= submax; ++sub) {
          const int c0   = C + (sub << 6);
          const int M    = s0 - c0;                          // >= 0, mult of 16
          const int tmin = (M >= 64) ? 0 : ((64 - M) >> 4);  // skip all-(n<0)
          const float* ep = e + ((size_t)(h * L + (2111 - M - ln))) * D + (quad << 3);
          const int sbase = (quad << 2) * (LDS2 + 1) + (sub << 6) + 80 - ln;
#pragma unroll
          for (int tt = 0; tt < 5; ++tt) {
            if (tt < tmin) continue;
            const float* ept = ep - (tt << 10);    // -16t e-rows (1024 floats)
            bf16x8 b0 = load_cvt8(ept);
            bf16x8 b1 = load_cvt8(ept + 32);
            f32x4 z = {0.f, 0.f, 0.f, 0.f};
            z         = __builtin_amdgcn_mfma_f32_16x16x32_bf16(a0, b0, z, 0, 0, 0);
            f32x4 acc = __builtin_amdgcn_mfma_f32_16x16x32_bf16(a1, b1, z, 0, 0, 0);
#pragma unroll
            for (int jr = 0; jr < 4; ++jr)
              ldsw[sbase + jr * (LDS2 + 1) - (tt << 4)] = acc[jr];
          }
        }

        // ---- store: 16 rows x 1 KB contiguous wave-stores ----
#pragma unroll
        for (int rr = 0; rr < 16; ++rr) {
          f32x4 o = *(const f32x4*)&ldsw[rr * LDS2 + 16 + (lane << 2)];
          if (mask) {
            const int cb = C + (lane << 2);      // col of o[0]
            const int r  = s0 + rr;
#pragma unroll
            for (int t2 = 0; t2 < 4; ++t2) if (cb + t2 > r) o[t2] = 0.f;
          }
          __builtin_nontemporal_store(o, (f32x4*)(orow + (size_t)rr * L));
        }
      } else {
        // ---- pure zero superchunk: 16 x 1 KB zero row-stores ----
        const f32x4 zz = {0.f, 0.f, 0.f, 0.f};
#pragma unroll
        for (int rr = 0; rr < 16; ++rr)
          __builtin_nontemporal_store(zz, (f32x4*)(orow + (size_t)rr * L));
      }
    }
  }
}

extern "C" void kernel_launch(void* const* d_in, const int* in_sizes, int n_in,
                              void* d_out, int out_size, void* d_ws, size_t ws_size,
                              hipStream_t stream) {
  const float* q = (const float*)d_in[0];   // (2, 8, 2048, 64) fp32
  const float* e = (const float*)d_in[1];   // (8, 2048, 64) fp32
  float* out = (float*)d_out;               // (2, 8, 2048, 2048) fp32

  dim3 grid(16, 16);   // (bh, 4-pair group) -> 256 blocks, 8 waves each
  skew_sc<<<grid, 512, 0, stream>>>(q, e, out);
}

// Round 5
// 285.828 us; speedup vs baseline: 1.1624x; 1.1115x over previous
//
#include <hip/hip_runtime.h>
#include <hip/hip_bf16.h>

// out[i, r, c] = dot(q[i, r, :], e[h, L-1-(r-c), :])  for c <= r, else 0
// T[r, n] = q[r,:] . e_rev[n,:]  (n = r - c).
//
// DIAGONAL-BAND LDS RESIDENCY: previous rounds re-read e from global per
// chunk (692 MB for a 4.2 MB array; the 268 MB write stream thrashes L2, so
// these miss -> ~155 us kernel, write-schedule-invariant).  Now chunks are
// partitioned by band M = s0-c0: group k only needs e_rev rows
// n in [128k-64, 128k+128) = 192 rows = 24 KB bf16, preloaded ONCE into
// XOR-swizzled LDS.  Block = (bh i, pair p, seg): groups K0=p, K1=15-p.
//
// Chunk enumeration (16-row x 64-col chunks, per bh):
//   compute: cblk = (s0>>6) - (2Kg + a),  a in {0,1}  (valid iff >= 0)
//   zero   : cblk = (s0>>6) + (2Kg + 1 + a)           (valid iff <= 31)
// Over p = 0..7, g,a in {0,1}: offsets 2Kg+a cover 0..31 and 2Kg+1+a cover
// 1..32, each EXACTLY once -> every chunk of every row-strip written once.
// Pair totals are constant (264 compute + 248 zero) -> balanced blocks;
// waves sample u = w + 8*seg + 16*t over u = sel*128 + s0i (sel = (g,a)),
// so each wave gets all 4 (g,a) x 8 evenly-spread s0i -> balanced waves.
//
// Per chunk (verified rounds 2-4 machinery, B now from LDS):
//   M = (s0&63) + 64a + 128Kg; subtile tt: n = M-64+16tt+ln,
//   elds row = n - (128Kg-64) = (s0&63) + 64a + 16tt + ln  (in [0,192))
//   tmin skips n<0 subtiles (M mult of 16 -> first included starts at n=0;
//   rows < 64 of a Kg=0 group are never read).  Diag (M<64): mask c>r.
//   Skewed per-wave staging lds[16][100] -> aligned f32x4 stores (verified).
// e-LDS swizzle: byte ^= (row&7)<<4 (ushort idx ^= (row&7)<<3) on write and
// read -> ds_read_b128 across 16 rows spreads banks (~2-way, free).

typedef __bf16 bf16x8 __attribute__((ext_vector_type(8)));
typedef float  f32x4  __attribute__((ext_vector_type(4)));
typedef float  f32x8  __attribute__((ext_vector_type(8)));

constexpr int L     = 2048;
constexpr int D     = 64;
constexpr int LDW   = 100;   // staging row stride (floats)
constexpr int EROWS = 192;   // e-window rows per group

__device__ __forceinline__ bf16x8 load_cvt8(const float* __restrict__ p) {
  f32x8 v = *(const f32x8*)p;       // 2x global_load_dwordx4
  bf16x8 r;
#pragma unroll
  for (int k = 0; k < 8; ++k) r[k] = (__bf16)v[k];
  return r;
}

__global__ __launch_bounds__(512) void skew_band(const float* __restrict__ q,
                                                 const float* __restrict__ e,
                                                 float* __restrict__ out) {
  const int tid  = threadIdx.x;
  const int lane = tid & 63;
  const int w    = tid >> 6;        // wave 0..7
  const int ln   = lane & 15;
  const int quad = lane >> 4;
  const int i    = blockIdx.x;      // bh index, h = i & 7
  const int h    = i & 7;
  const int p    = blockIdx.y;      // pair 0..7: groups K0 = p, K1 = 15-p
  const int seg  = blockIdx.z;      // 0..1

  __shared__ ushort elds[2 * EROWS * 64];   // bf16 e-windows, swizzled, 48 KB
  __shared__ __align__(16) float stg[8 * 16 * LDW];  // per-wave staging, 51.2 KB

  // ---- cooperative e-window preload (both groups), one barrier ----
  {
    const int rcol = tid & 7;                 // 32 B column within row
#pragma unroll
    for (int g = 0; g < 2; ++g) {
      const int Kg    = g ? (15 - p) : p;
      const int nbase = (Kg << 7) - 64;
#pragma unroll
      for (int pass = 0; pass < 3; ++pass) {
        const int row = (tid >> 3) + (pass << 6);   // 0..191
        const int n   = nbase + row;                // in [-64, 2047]
        if (n >= 0) {
          const int erow = 2047 - n;
          bf16x8 v = load_cvt8(e + ((size_t)(h * L + erow)) * D + rcol * 8);
          *(bf16x8*)&elds[g * (EROWS * 64) + row * 64 +
                          ((rcol * 8) ^ ((row & 7) << 3))] = v;
        }
      }
    }
  }
  __syncthreads();

  float* obase = out + (size_t)i * L * L;
  float* ldsw  = &stg[w * (16 * LDW)];

#pragma unroll 1
  for (int t = 0; t < 32; ++t) {
    const int u   = w + (seg << 3) + (t << 4);   // 0..511, disjoint cover
    const int s0i = u & 127;
    const int sel = u >> 7;                      // 0..3
    const int g   = sel & 1;
    const int a   = sel >> 1;
    const int s0  = s0i << 4;
    const int Kg  = g ? (15 - p) : p;

    const int cb = (s0 >> 6) - 2 * Kg - a;
    if (cb >= 0) {
      // ---- compute chunk (s0, c0) ----
      const int c0   = cb << 6;
      const int M    = s0 - c0;                          // = (s0&63)+64a+128Kg
      const int tmin = (M >= 64) ? 0 : ((64 - M) >> 4);
      const bool mask = (M < 64);                        // only Kg=0, a=0
      const int rowb = (s0 & 63) + (a << 6);             // elds row base
      const int gbase = g * (EROWS * 64);

      const float* qp = q + ((size_t)(i * L + s0 + ln)) * D + (quad << 3);
      const bf16x8 a0 = load_cvt8(qp);
      const bf16x8 a1 = load_cvt8(qp + 32);

      f32x4 acc[5];
#pragma unroll
      for (int tt = 0; tt < 5; ++tt) {
        if (tt < tmin) continue;
        const int row = rowb + (tt << 4) + ln;           // <= 191
        const int rb  = gbase + row * 64;
        const int sw  = (row & 7) << 3;
        const bf16x8 b0 = *(const bf16x8*)&elds[rb + (((quad << 3)     ) ^ sw)];
        const bf16x8 b1 = *(const bf16x8*)&elds[rb + ((32 + (quad << 3)) ^ sw)];
        f32x4 z = {0.f, 0.f, 0.f, 0.f};
        z       = __builtin_amdgcn_mfma_f32_16x16x32_bf16(a0, b0, z, 0, 0, 0);
        acc[tt] = __builtin_amdgcn_mfma_f32_16x16x32_bf16(a1, b1, z, 0, 0, 0);
      }

      // skewed staging: row = quad*4+jr, g-col = 15+16tt+ln-4quad-jr
      const int lbase = quad * (4 * LDW - 4) + ln + 15;
#pragma unroll
      for (int tt = 0; tt < 5; ++tt) {
        if (tt < tmin) continue;
#pragma unroll
        for (int jr = 0; jr < 4; ++jr)
          ldsw[lbase + jr * (LDW - 1) + (tt << 4)] = acc[tt][jr];
      }

      // diagonal-aligned reads + 16 B stores (stale LDS lies in masked c>r)
      float* orow = obase + (size_t)s0 * L + c0;
#pragma unroll
      for (int it = 0; it < 4; ++it) {
        const int idx = (it << 6) + lane;
        const int rr  = idx >> 4;
        const int jj  = idx & 15;
        const f32x4 v = *(const f32x4*)&ldsw[rr * LDW + 76 - (jj << 2)];
        f32x4 o = { v[3], v[2], v[1], v[0] };
        if (mask) {
          const int lim = M + rr - (jj << 2);   // t2 > lim -> c > r
#pragma unroll
          for (int t2 = 0; t2 < 4; ++t2) if (t2 > lim) o[t2] = 0.f;
        }
        __builtin_nontemporal_store(
            o, (f32x4*)(orow + (size_t)rr * L + (jj << 2)));
      }
    }

    const int cbz = (s0 >> 6) + 2 * Kg + 1 + a;
    if (cbz <= 31) {
      // ---- pure zero chunk (s0, cbz*64) ----
      float* orow = obase + (size_t)s0 * L + (cbz << 6);
      const f32x4 zz = {0.f, 0.f, 0.f, 0.f};
#pragma unroll
      for (int it = 0; it < 4; ++it) {
        const int idx = (it << 6) + lane;
        const int rr  = idx >> 4;
        const int jj  = idx & 15;
        __builtin_nontemporal_store(
            zz, (f32x4*)(orow + (size_t)rr * L + (jj << 2)));
      }
    }
  }
}

extern "C" void kernel_launch(void* const* d_in, const int* in_sizes, int n_in,
                              void* d_out, int out_size, void* d_ws, size_t ws_size,
                              hipStream_t stream) {
  const float* q = (const float*)d_in[0];   // (2, 8, 2048, 64) fp32
  const float* e = (const float*)d_in[1];   // (8, 2048, 64) fp32
  float* out = (float*)d_out;               // (2, 8, 2048, 2048) fp32

  dim3 grid(16, 8, 2);   // (bh, band-pair, segment) = 256 blocks, 8 waves each
  skew_band<<<grid, 512, 0, stream>>>(q, e, out);
}

// Round 6
// 274.075 us; speedup vs baseline: 1.2123x; 1.0429x over previous
//
#include <hip/hip_runtime.h>
#include <hip/hip_bf16.h>

// out[i, r, c] = dot(q[i, r, :], e[h, L-1-(r-c), :])  for c <= r, else 0
// T[r, n] = q[r,:] . e_rev[n,:]  (n = r - c).
//
// Round-5 band-LDS structure (e_rev windows resident in swizzled LDS, chunk
// set per wave identical), with two changes:
//  1) PLAIN stores instead of __builtin_nontemporal_store: NT (evict-first)
//     was in every prior kernel and is the prime suspect for the ~2.3 TB/s
//     effective write BW vs the fill's 6.4 TB/s on the plain writeback path.
//  2) STRIP-MAJOR order + q prefetch: each wave visits its 8 strips, doing
//     all 4 sels of a strip consecutively -> q fragments loaded once per
//     strip (was 4x), and the NEXT strip's q is loaded (raw f32) at the top
//     of the current strip so its latency hides under ~15 us of work.
//     Same chunk multiset per wave as round 5 (pure reorder; balance and
//     coverage proofs unchanged).
//
// Chunk enumeration per (i, p): strip s0i covered by exactly one wave
// (s0i = w + 8*seg + 16*k), which does sel = (a,g) in 0..3:
//   compute: cblk = (s0i>>2) - (2Kg + a)   (valid iff >= 0)
//   zero   : cblk = (s0i>>2) + (2Kg + 1+a) (valid iff <= 31)
// Over p = 0..7, g,a: offsets cover 0..31 / 1..32 exactly once.
//
// Per chunk (verified rounds 2-5 machinery):
//   M = (s0&63) + 64a + 128Kg; subtile tt: n = M-64+16tt+ln,
//   elds row = (s0&63) + 64a + 16tt + ln  (max 112+79 = 191 < 192, s0&63
//   in {0,16,32,48});  tmin skips n<0 subtiles.  Diag (M<64): mask c>r.
//   Skewed per-wave staging stg[16][100] -> aligned f32x4 stores.
// e-LDS swizzle: ushort idx ^= (row&7)<<3 on write and read.

typedef __bf16 bf16x8 __attribute__((ext_vector_type(8)));
typedef float  f32x4  __attribute__((ext_vector_type(4)));
typedef float  f32x8  __attribute__((ext_vector_type(8)));

constexpr int L     = 2048;
constexpr int D     = 64;
constexpr int LDW   = 100;   // staging row stride (floats)
constexpr int EROWS = 192;   // e-window rows per group

__device__ __forceinline__ bf16x8 cvt8(f32x8 v) {
  bf16x8 r;
#pragma unroll
  for (int k = 0; k < 8; ++k) r[k] = (__bf16)v[k];
  return r;
}

__device__ __forceinline__ bf16x8 load_cvt8(const float* __restrict__ p) {
  return cvt8(*(const f32x8*)p);
}

__global__ __launch_bounds__(512) void skew_band(const float* __restrict__ q,
                                                 const float* __restrict__ e,
                                                 float* __restrict__ out) {
  const int tid  = threadIdx.x;
  const int lane = tid & 63;
  const int w    = tid >> 6;        // wave 0..7
  const int ln   = lane & 15;
  const int quad = lane >> 4;
  const int i    = blockIdx.x;      // bh index, h = i & 7
  const int h    = i & 7;
  const int p    = blockIdx.y;      // pair 0..7: groups K0 = p, K1 = 15-p
  const int seg  = blockIdx.z;      // 0..1

  __shared__ ushort elds[2 * EROWS * 64];   // bf16 e-windows, swizzled, 48 KB
  __shared__ __align__(16) float stg[8 * 16 * LDW];  // per-wave staging, 51.2 KB

  // ---- cooperative e-window preload (both groups), one barrier ----
  {
    const int rcol = tid & 7;                 // 32 B column within row
#pragma unroll
    for (int g = 0; g < 2; ++g) {
      const int Kg    = g ? (15 - p) : p;
      const int nbase = (Kg << 7) - 64;
#pragma unroll
      for (int pass = 0; pass < 3; ++pass) {
        const int row = (tid >> 3) + (pass << 6);   // 0..191
        const int n   = nbase + row;                // in [-64, 2047]
        if (n >= 0) {
          const int erow = 2047 - n;
          bf16x8 v = load_cvt8(e + ((size_t)(h * L + erow)) * D + rcol * 8);
          *(bf16x8*)&elds[g * (EROWS * 64) + row * 64 +
                          ((rcol * 8) ^ ((row & 7) << 3))] = v;
        }
      }
    }
  }
  __syncthreads();

  float* obase = out + (size_t)i * L * L;
  float* ldsw  = &stg[w * (16 * LDW)];

  const int s0i0 = w + (seg << 3);            // first strip; step 16
  const float* qbase = q + ((size_t)(i * L + (s0i0 << 4) + ln)) * D + (quad << 3);

  // prefetched raw q for the current strip (consumed at loop top)
  f32x8 r0 = *(const f32x8*)qbase;
  f32x8 r1 = *(const f32x8*)(qbase + 32);

#pragma unroll 1
  for (int k = 0; k < 8; ++k) {
    const bf16x8 a0 = cvt8(r0);
    const bf16x8 a1 = cvt8(r1);
    if (k < 7) {                              // prefetch next strip's q
      const float* qn = qbase + (size_t)(k + 1) * (256 * D);
      r0 = *(const f32x8*)qn;
      r1 = *(const f32x8*)(qn + 32);
    }

    const int s0i = s0i0 + (k << 4);
    const int s0  = s0i << 4;
    const int cbb = s0i >> 2;

#pragma unroll 1
    for (int sel = 0; sel < 4; ++sel) {
      const int g  = sel & 1;
      const int a  = sel >> 1;
      const int Kg = g ? (15 - p) : p;

      const int cb = cbb - 2 * Kg - a;
      if (cb >= 0) {
        // ---- compute chunk (s0, c0) ----
        const int c0    = cb << 6;
        const int M     = s0 - c0;                          // = (s0&63)+64a+128Kg
        const int tmin  = (M >= 64) ? 0 : ((64 - M) >> 4);
        const bool mask = (M < 64);                         // only Kg=0, a=0
        const int rowb  = (s0 & 63) + (a << 6);             // elds row base
        const int gbase = g * (EROWS * 64);

        f32x4 acc[5];
#pragma unroll
        for (int tt = 0; tt < 5; ++tt) {
          if (tt < tmin) continue;
          const int row = rowb + (tt << 4) + ln;            // <= 191
          const int rb  = gbase + row * 64;
          const int sw  = (row & 7) << 3;
          const bf16x8 b0 = *(const bf16x8*)&elds[rb + (((quad << 3)     ) ^ sw)];
          const bf16x8 b1 = *(const bf16x8*)&elds[rb + ((32 + (quad << 3)) ^ sw)];
          f32x4 z = {0.f, 0.f, 0.f, 0.f};
          z       = __builtin_amdgcn_mfma_f32_16x16x32_bf16(a0, b0, z, 0, 0, 0);
          acc[tt] = __builtin_amdgcn_mfma_f32_16x16x32_bf16(a1, b1, z, 0, 0, 0);
        }

        // skewed staging: row = quad*4+jr, g-col = 15+16tt+ln-4quad-jr
        const int lbase = quad * (4 * LDW - 4) + ln + 15;
#pragma unroll
        for (int tt = 0; tt < 5; ++tt) {
          if (tt < tmin) continue;
#pragma unroll
          for (int jr = 0; jr < 4; ++jr)
            ldsw[lbase + jr * (LDW - 1) + (tt << 4)] = acc[tt][jr];
        }

        // diagonal-aligned reads + PLAIN 16 B stores
        float* orow = obase + (size_t)s0 * L + c0;
#pragma unroll
        for (int it = 0; it < 4; ++it) {
          const int idx = (it << 6) + lane;
          const int rr  = idx >> 4;
          const int jj  = idx & 15;
          const f32x4 v = *(const f32x4*)&ldsw[rr * LDW + 76 - (jj << 2)];
          f32x4 o = { v[3], v[2], v[1], v[0] };
          if (mask) {
            const int lim = M + rr - (jj << 2);   // t2 > lim -> c > r
#pragma unroll
            for (int t2 = 0; t2 < 4; ++t2) if (t2 > lim) o[t2] = 0.f;
          }
          *(f32x4*)(orow + (size_t)rr * L + (jj << 2)) = o;
        }
      }

      const int cbz = cbb + 2 * Kg + 1 + a;
      if (cbz <= 31) {
        // ---- pure zero chunk (s0, cbz*64), PLAIN stores ----
        float* orow = obase + (size_t)s0 * L + (cbz << 6);
        const f32x4 zz = {0.f, 0.f, 0.f, 0.f};
#pragma unroll
        for (int it = 0; it < 4; ++it) {
          const int idx = (it << 6) + lane;
          const int rr  = idx >> 4;
          const int jj  = idx & 15;
          *(f32x4*)(orow + (size_t)rr * L + (jj << 2)) = zz;
        }
      }
    }
  }
}

extern "C" void kernel_launch(void* const* d_in, const int* in_sizes, int n_in,
                              void* d_out, int out_size, void* d_ws, size_t ws_size,
                              hipStream_t stream) {
  const float* q = (const float*)d_in[0];   // (2, 8, 2048, 64) fp32
  const float* e = (const float*)d_in[1];   // (8, 2048, 64) fp32
  float* out = (float*)d_out;               // (2, 8, 2048, 2048) fp32

  dim3 grid(16, 8, 2);   // (bh, band-pair, segment) = 256 blocks, 8 waves each
  skew_band<<<grid, 512, 0, stream>>>(q, e, out);
}

// Round 7
// 263.178 us; speedup vs baseline: 1.2625x; 1.0414x over previous
//
#include <hip/hip_runtime.h>
#include <hip/hip_bf16.h>

// out[i, r, c] = dot(q[i, r, :], e[h, L-1-(r-c), :])  for c <= r, else 0
// T[r, n] = q[r,:] . e_rev[n,:]  (n = r - c).
//
// Round-6 structure (band-resident e in swizzled LDS, strip-major q with
// prefetch, plain stores) with two changes:
//  1) ZEROS VIA hipMemsetAsync: the upper triangle (134 MB of zeros) is
//     written by the memset path proven at 6.5 TB/s by the harness's own
//     fill; the kernel writes ONLY lower-triangle compute chunks (134 MB),
//     halving its store traffic.  Zero-chunk code deleted.
//  2) 256-thread blocks (4 waves), LDS 48+25.6 = 73.6 KB -> 2 blocks/CU
//     (two independent store streams per CU).  Grid (16, 8, 4).
//
// Chunk enumeration per (i, p): strip class cls = w + 4*seg in 0..15,
// strips s0i = cls + 16k.  sel = (a,g): compute chunk at
// cblk = (s0i>>2) - (2Kg + a), valid iff >= 0.  Over p, g, a the offsets
// 2K+a cover 0..31 exactly once -> every lower-tri chunk written once;
// strictly-upper chunks are memset-only.  Compute chunks per band-pair
// = (63-4p)*4 + (63-4(15-p))*4 = 264 for every p -> balanced blocks.
//
// Per chunk (verified rounds 2-6 machinery):
//   M = (s0&63) + 64a + 128Kg; subtile tt: n = M-64+16tt+ln,
//   elds row = (s0&63) + 64a + 16tt + ln  (<= 191); tmin skips n<0
//   subtiles.  Diag (M<64): mask c>r (covers stale-LDS garbage too; the
//   masked zeros land on memset zeros, harmless).
//   Skewed per-wave staging stg[16][100] -> aligned f32x4 plain stores.
// e-LDS swizzle: ushort idx ^= (row&7)<<3 on write and read.

typedef __bf16 bf16x8 __attribute__((ext_vector_type(8)));
typedef float  f32x4  __attribute__((ext_vector_type(4)));
typedef float  f32x8  __attribute__((ext_vector_type(8)));

constexpr int L     = 2048;
constexpr int D     = 64;
constexpr int LDW   = 100;   // staging row stride (floats)
constexpr int EROWS = 192;   // e-window rows per group

__device__ __forceinline__ bf16x8 cvt8(f32x8 v) {
  bf16x8 r;
#pragma unroll
  for (int k = 0; k < 8; ++k) r[k] = (__bf16)v[k];
  return r;
}

__device__ __forceinline__ bf16x8 load_cvt8(const float* __restrict__ p) {
  return cvt8(*(const f32x8*)p);
}

__global__ __launch_bounds__(256) void skew_band(const float* __restrict__ q,
                                                 const float* __restrict__ e,
                                                 float* __restrict__ out) {
  const int tid  = threadIdx.x;
  const int lane = tid & 63;
  const int w    = tid >> 6;        // wave 0..3
  const int ln   = lane & 15;
  const int quad = lane >> 4;
  const int i    = blockIdx.x;      // bh index, h = i & 7
  const int h    = i & 7;
  const int p    = blockIdx.y;      // pair 0..7: groups K0 = p, K1 = 15-p
  const int seg  = blockIdx.z;      // 0..3

  __shared__ ushort elds[2 * EROWS * 64];            // 48 KB, swizzled bf16
  __shared__ __align__(16) float stg[4 * 16 * LDW];  // 25.6 KB per-wave staging

  // ---- cooperative e-window preload (both groups), one barrier ----
  {
    const int rcol = tid & 7;                 // 32 B column within row
#pragma unroll
    for (int g = 0; g < 2; ++g) {
      const int Kg    = g ? (15 - p) : p;
      const int nbase = (Kg << 7) - 64;
#pragma unroll
      for (int pass = 0; pass < 6; ++pass) {
        const int row = (tid >> 3) + (pass << 5);   // 0..191
        const int n   = nbase + row;                // in [-64, 2047]
        if (n >= 0) {
          const int erow = 2047 - n;
          bf16x8 v = load_cvt8(e + ((size_t)(h * L + erow)) * D + rcol * 8);
          *(bf16x8*)&elds[g * (EROWS * 64) + row * 64 +
                          ((rcol * 8) ^ ((row & 7) << 3))] = v;
        }
      }
    }
  }
  __syncthreads();

  float* obase = out + (size_t)i * L * L;
  float* ldsw  = &stg[w * (16 * LDW)];

  const int cls = w + (seg << 2);             // strip class 0..15
  const float* qbase = q + ((size_t)(i * L + (cls << 4) + ln)) * D + (quad << 3);

  // prefetched raw q for the current strip (consumed at loop top)
  f32x8 r0 = *(const f32x8*)qbase;
  f32x8 r1 = *(const f32x8*)(qbase + 32);

#pragma unroll 1
  for (int k = 0; k < 8; ++k) {
    const bf16x8 a0 = cvt8(r0);
    const bf16x8 a1 = cvt8(r1);
    if (k < 7) {                              // prefetch next strip's q
      const float* qn = qbase + (size_t)(k + 1) * (256 * D);
      r0 = *(const f32x8*)qn;
      r1 = *(const f32x8*)(qn + 32);
    }

    const int s0i = cls + (k << 4);
    const int s0  = s0i << 4;
    const int cbb = s0i >> 2;

#pragma unroll 1
    for (int sel = 0; sel < 4; ++sel) {
      const int g  = sel & 1;
      const int a  = sel >> 1;
      const int Kg = g ? (15 - p) : p;

      const int cb = cbb - 2 * Kg - a;
      if (cb < 0) continue;

      // ---- compute chunk (s0, c0) ----
      const int c0    = cb << 6;
      const int M     = s0 - c0;                          // = (s0&63)+64a+128Kg
      const int tmin  = (M >= 64) ? 0 : ((64 - M) >> 4);
      const bool mask = (M < 64);                         // only Kg=0, a=0
      const int rowb  = (s0 & 63) + (a << 6);             // elds row base
      const int gbase = g * (EROWS * 64);

      f32x4 acc[5];
#pragma unroll
      for (int tt = 0; tt < 5; ++tt) {
        if (tt < tmin) continue;
        const int row = rowb + (tt << 4) + ln;            // <= 191
        const int rb  = gbase + row * 64;
        const int sw  = (row & 7) << 3;
        const bf16x8 b0 = *(const bf16x8*)&elds[rb + (((quad << 3)     ) ^ sw)];
        const bf16x8 b1 = *(const bf16x8*)&elds[rb + ((32 + (quad << 3)) ^ sw)];
        f32x4 z = {0.f, 0.f, 0.f, 0.f};
        z       = __builtin_amdgcn_mfma_f32_16x16x32_bf16(a0, b0, z, 0, 0, 0);
        acc[tt] = __builtin_amdgcn_mfma_f32_16x16x32_bf16(a1, b1, z, 0, 0, 0);
      }

      // skewed staging: row = quad*4+jr, g-col = 15+16tt+ln-4quad-jr
      const int lbase = quad * (4 * LDW - 4) + ln + 15;
#pragma unroll
      for (int tt = 0; tt < 5; ++tt) {
        if (tt < tmin) continue;
#pragma unroll
        for (int jr = 0; jr < 4; ++jr)
          ldsw[lbase + jr * (LDW - 1) + (tt << 4)] = acc[tt][jr];
      }

      // diagonal-aligned reads + plain 16 B stores
      float* orow = obase + (size_t)s0 * L + c0;
#pragma unroll
      for (int it = 0; it < 4; ++it) {
        const int idx = (it << 6) + lane;
        const int rr  = idx >> 4;
        const int jj  = idx & 15;
        const f32x4 v = *(const f32x4*)&ldsw[rr * LDW + 76 - (jj << 2)];
        f32x4 o = { v[3], v[2], v[1], v[0] };
        if (mask) {
          const int lim = M + rr - (jj << 2);   // t2 > lim -> c > r
#pragma unroll
          for (int t2 = 0; t2 < 4; ++t2) if (t2 > lim) o[t2] = 0.f;
        }
        *(f32x4*)(orow + (size_t)rr * L + (jj << 2)) = o;
      }
    }
  }
}

extern "C" void kernel_launch(void* const* d_in, const int* in_sizes, int n_in,
                              void* d_out, int out_size, void* d_ws, size_t ws_size,
                              hipStream_t stream) {
  const float* q = (const float*)d_in[0];   // (2, 8, 2048, 64) fp32
  const float* e = (const float*)d_in[1];   // (8, 2048, 64) fp32
  float* out = (float*)d_out;               // (2, 8, 2048, 2048) fp32

  // Upper-triangle zeros via the proven-fast fill path (capture-legal).
  hipMemsetAsync(d_out, 0, (size_t)out_size, stream);

  dim3 grid(16, 8, 4);   // (bh, band-pair, seg) = 512 blocks, 4 waves each
  skew_band<<<grid, 256, 0, stream>>>(q, e, out);
}

// Round 8
// 262.599 us; speedup vs baseline: 1.2652x; 1.0022x over previous
//
#include <hip/hip_runtime.h>
#include <hip/hip_bf16.h>

// out[i, r, c] = dot(q[i, r, :], e[h, L-1-(r-c), :])  for c <= r, else 0
// T[r, n] = q[r,:] . e_rev[n,:]  (n = r - c).
//
// PAGE-CLUSTERED stores + LDS-resident e.  Prior rounds: each 1-KB output
// page (256 floats of a row) was written as 4x 256-B quarters by TWO
// different blocks (band-offsets d0..d0+3 span two K-pairs) at arbitrary
// times -> ~25% DRAM page efficiency -> kernel store BW capped ~2.5 TB/s.
// Now block (i, pm, seg) owns ADJACENT band quads d in {4pm..4pm+3} and
// {4(7-pm)..4(7-pm)+3}; per strip one wave computes the up-to-4 adjacent
// chunks consecutively, holds them in registers (o[4][4] f32x4), then
// writes each row's full 1 KB as 4 back-to-back wave-stores.
// Pairing m=pm with 7-pm keeps block totals exactly 528 chunks/bh.
//
// Chunk algebra (d = cbb - cblk, cbb = s0i>>2):
//   M = s0 - c0 = 16(s0i&3) + 64d;  dd = d & 3 (within quad, d = 4*mg+dd)
//   e-window for quad mg: n in [256*mg - 64, 256*mg + 256) = 320 rows,
//   bf16-swizzled in LDS (idx ^= (row&7)<<3); subtile tt reads window row
//   = 16(s0i&3) + 64*dd + 16*tt + ln  (in [0,320)).  tmin skips n<0
//   subtiles (only d=0); diag mask (M<64, only d=0) zeroes c>r, which also
//   covers stale skew-staging data from skipped subtiles (those positions
//   are exactly n<0 ⟺ c>r).  Valid dd per strip: 0..min(3, cbb-4*mg);
//   valid cblks are contiguous ascending -> full-page runs.
// Upper triangle: hipMemsetAsync (proven 6.4 TB/s fill path).
// LDS: 2x320x64 bf16 windows (80 KB) + 8x [16][100] skew staging (51.2 KB)
// = 131.2 KB -> 1 block/CU, 8 waves (2/SIMD).  Grid (16, 4, 4).

typedef __bf16 bf16x8 __attribute__((ext_vector_type(8)));
typedef float  f32x4  __attribute__((ext_vector_type(4)));
typedef float  f32x8  __attribute__((ext_vector_type(8)));

constexpr int L   = 2048;
constexpr int D   = 64;
constexpr int LDW = 100;    // skew staging row stride (floats)
constexpr int EW  = 320;    // e-window rows per quad

__device__ __forceinline__ bf16x8 cvt8(f32x8 v) {
  bf16x8 r;
#pragma unroll
  for (int k = 0; k < 8; ++k) r[k] = (__bf16)v[k];
  return r;
}

__device__ __forceinline__ bf16x8 load_cvt8(const float* __restrict__ p) {
  return cvt8(*(const f32x8*)p);
}

__global__ __launch_bounds__(512) void skew_page(const float* __restrict__ q,
                                                 const float* __restrict__ e,
                                                 float* __restrict__ out) {
  const int tid  = threadIdx.x;
  const int lane = tid & 63;
  const int w    = tid >> 6;        // wave 0..7
  const int ln   = lane & 15;
  const int quad = lane >> 4;
  const int i    = blockIdx.x;      // bh index, h = i & 7
  const int h    = i & 7;
  const int pm   = blockIdx.y;      // 0..3: quads mg0 = pm, mg1 = 7-pm
  const int seg  = blockIdx.z;      // 0..3

  __shared__ __align__(16) ushort elds[2 * EW * 64];   // 80 KB swizzled bf16
  __shared__ __align__(16) float stg[8 * 16 * LDW];    // 51.2 KB per-wave skew

  // ---- cooperative e-window preload (two 320-row quad windows) ----
  {
    const int rcol = tid & 7;                 // 32 B column within row
#pragma unroll
    for (int g = 0; g < 2; ++g) {
      const int mg    = g ? (7 - pm) : pm;
      const int nbase = (mg << 8) - 64;
#pragma unroll
      for (int pass = 0; pass < 5; ++pass) {
        const int row = (tid >> 3) + (pass << 6);   // 0..319
        const int n   = nbase + row;                // in [-64, 2047]
        if (n >= 0) {
          const int erow = 2047 - n;
          bf16x8 v = load_cvt8(e + ((size_t)(h * L + erow)) * D + rcol * 8);
          *(bf16x8*)&elds[g * (EW * 64) + row * 64 +
                          ((rcol * 8) ^ ((row & 7) << 3))] = v;
        }
      }
    }
  }
  __syncthreads();

  float* obase = out + (size_t)i * L * L;
  float* ldsw  = &stg[w * (16 * LDW)];

  const int cls = w + (seg << 3);             // strip class 0..31
  const float* qbase = q + ((size_t)(i * L + (cls << 4) + ln)) * D + (quad << 3);

  // prefetched raw q for the current strip (consumed at loop top)
  f32x8 r0 = *(const f32x8*)qbase;
  f32x8 r1 = *(const f32x8*)(qbase + 32);

#pragma unroll 1
  for (int k = 0; k < 4; ++k) {
    const bf16x8 a0 = cvt8(r0);
    const bf16x8 a1 = cvt8(r1);
    if (k < 3) {                              // prefetch next strip's q
      const float* qn = qbase + (size_t)(k + 1) * (512 * D);
      r0 = *(const f32x8*)qn;
      r1 = *(const f32x8*)(qn + 32);
    }

    const int s0i  = cls + (k << 5);          // strip index 0..127
    const int s0   = s0i << 4;
    const int cbb  = s0i >> 2;
    const int rb16 = (s0i & 3) << 4;          // 16*(s0i&3)

#pragma unroll 1
    for (int g = 0; g < 2; ++g) {
      const int mg    = g ? (7 - pm) : pm;
      const int d0    = mg << 2;
      const int ddmax = cbb - d0;             // valid dd: 0..min(3,ddmax)
      if (ddmax < 0) continue;
      const int gbase = g * (EW * 64);

      f32x4 o[4][4];                          // [dd][it], static-indexed

#pragma unroll
      for (int dd = 0; dd < 4; ++dd) {
        if (dd > ddmax) continue;
        const int d    = d0 + dd;
        const int M    = rb16 + (d << 6);                 // 16(s0i&3)+64d
        const int tmin = (M >= 64) ? 0 : ((64 - M) >> 4); // only d=0
        const int rowb = rb16 + (dd << 6);                // window row base

        f32x4 acc[5];
#pragma unroll
        for (int tt = 0; tt < 5; ++tt) {
          if (tt < tmin) continue;
          const int row = rowb + (tt << 4) + ln;          // <= 319
          const int rbx = gbase + row * 64;
          const int sw  = (row & 7) << 3;
          const bf16x8 b0 = *(const bf16x8*)&elds[rbx + (((quad << 3)     ) ^ sw)];
          const bf16x8 b1 = *(const bf16x8*)&elds[rbx + ((32 + (quad << 3)) ^ sw)];
          f32x4 z = {0.f, 0.f, 0.f, 0.f};
          z       = __builtin_amdgcn_mfma_f32_16x16x32_bf16(a0, b0, z, 0, 0, 0);
          acc[tt] = __builtin_amdgcn_mfma_f32_16x16x32_bf16(a1, b1, z, 0, 0, 0);
        }

        // skew staging: row = quad*4+jr, col g' = 15+16tt+ln-4quad-jr
        const int lbase = quad * (4 * LDW - 4) + ln + 15;
#pragma unroll
        for (int tt = 0; tt < 5; ++tt) {
          if (tt < tmin) continue;
#pragma unroll
          for (int jr = 0; jr < 4; ++jr)
            ldsw[lbase + jr * (LDW - 1) + (tt << 4)] = acc[tt][jr];
        }

        // diagonal-aligned read-back into registers
        const bool mask = (M < 64);
#pragma unroll
        for (int it = 0; it < 4; ++it) {
          const int idx = (it << 6) + lane;
          const int rr  = idx >> 4;
          const int jj  = idx & 15;
          const f32x4 v = *(const f32x4*)&ldsw[rr * LDW + 76 - (jj << 2)];
          f32x4 oo = { v[3], v[2], v[1], v[0] };
          if (mask) {
            const int lim = M + rr - (jj << 2);   // t2 > lim -> c > r
#pragma unroll
            for (int t2 = 0; t2 < 4; ++t2) if (t2 > lim) oo[t2] = 0.f;
          }
          o[dd][it] = oo;
        }
      }

      // ---- page-clustered stores: per row-group, ascending cblk ----
#pragma unroll
      for (int it = 0; it < 4; ++it) {
        const int idx = (it << 6) + lane;
        const int rr  = idx >> 4;
        const int jj  = idx & 15;
        float* orowb = obase + (size_t)(s0 + rr) * L + (jj << 2);
#pragma unroll
        for (int dd = 3; dd >= 0; --dd) {     // cblk = cbb-d0-dd ascending
          if (dd > ddmax) continue;
          *(f32x4*)(orowb + ((cbb - d0 - dd) << 6)) = o[dd][it];
        }
      }
    }
  }
}

extern "C" void kernel_launch(void* const* d_in, const int* in_sizes, int n_in,
                              void* d_out, int out_size, void* d_ws, size_t ws_size,
                              hipStream_t stream) {
  const float* q = (const float*)d_in[0];   // (2, 8, 2048, 64) fp32
  const float* e = (const float*)d_in[1];   // (8, 2048, 64) fp32
  float* out = (float*)d_out;               // (2, 8, 2048, 2048) fp32

  // Upper-triangle zeros via the proven-fast fill path (capture-legal).
  hipMemsetAsync(d_out, 0, (size_t)out_size, stream);

  dim3 grid(16, 4, 4);   // (bh, adjacent-quad pair, seg), 512 threads
  skew_page<<<grid, 512, 0, stream>>>(q, e, out);
}